// Round 9
// baseline (137.643 us; speedup 1.0000x reference)
//
#include <hip/hip_runtime.h>
#include <math.h>

// ===========================================================================
// CrossAttentionLayer — collapsed attention + bf16-MFMA SwiGLU FF.
//
// kv is broadcast over j => softmax exactly uniform => attention out = v_row,
// independent of q (Wq unused):
//   attn_out[b,c] = sum_i vrow[b, i&63] * Wout[i,c],
//   vrow[b,:] = (LN(extra[b]) @ Wkv)[64:128].
// Per position: x = LN_C(cnn); h = x@W1; ff = (silu(h[512:])*h[:512])@W2;
//   out[b,c,p] = attn_out[b,c] + ff[p,c]
//
// Round-9 = Round-7 structure tuned for 3 blocks/CU (12 waves — decorrelate
// the per-chunk barrier lockstep that capped MfmaUtil at 24%):
//   - launch_bounds(256,3): budget 170 regs/wave (unified VGPR+AGPR).
//   - W1(0) prefetch moved AFTER the normalize (kills v[]/wx overlap that
//     cost 10 regs over the 3-wave budget; loads still fly over the BAR).
//   - w2f prefetch + setprio REMOVED (R8: measured neutral-to-negative).
//   - att row loaded in epilogue (frees 4 live regs in the loop).
// R6/R3 lesson: spills show as WRITE_SIZE ballooning — that's the tripwire.
// ===========================================================================

#define BATCH 16
#define CDIM  256
#define HW    4096

using short8 = __attribute__((ext_vector_type(8))) short;
using f32x4  = __attribute__((ext_vector_type(4))) float;
using u32x2  = __attribute__((ext_vector_type(2))) unsigned int;
using u32x4  = __attribute__((ext_vector_type(4))) unsigned int;
typedef unsigned int   u32;
typedef unsigned short u16;

__device__ __forceinline__ u16 f2bf(float f) {
    u32 u = __float_as_uint(f);
    u += 0x7fffu + ((u >> 16) & 1u);   // round-nearest-even
    return (u16)(u >> 16);
}

__device__ __forceinline__ u32 cvtpk_bf16(float lo, float hi) {
    u32 r;
    asm("v_cvt_pk_bf16_f32 %0, %1, %2" : "=v"(r) : "v"(lo), "v"(hi));
    return r;
}

// lgkm drain (LDS visibility) + barrier; NO vmcnt drain (global weight loads
// stay in flight across the barrier). "memory" pins compile-time order.
#define BAR() asm volatile("s_waitcnt lgkmcnt(0)\n\ts_barrier" ::: "memory")

// ---------------------------------------------------------------------------
// Prep (R8 form): blocks 0..63 attn-row partials (4x parallel); 64..127
// W1->frag-tiled; 128..159 W2->frag-tiled. Fragment-tiled index: element
// (row n, col cc) at (n>>4)*(Rr*16)+(cc>>5)*512+(n&15)*32+(cc&31).
// ---------------------------------------------------------------------------
__global__ void prep_kernel(const float* __restrict__ extra,
                            const float* __restrict__ ln2_g,
                            const float* __restrict__ ln2_b,
                            const float* __restrict__ Wkv,
                            const float* __restrict__ Wout,
                            const float* __restrict__ W1,
                            const float* __restrict__ W2,
                            float* __restrict__ attn_part,   // (4,16,256)
                            u16* __restrict__ w1t,
                            u16* __restrict__ w2t)
{
    const int t = threadIdx.x;
    if (blockIdx.x < 64) {
        __shared__ float e[512];
        __shared__ float red[256], red2[256];
        __shared__ float vpart[256];
        __shared__ float vrow[64];
        const int b    = blockIdx.x >> 2;
        const int part = blockIdx.x & 3;
        float a0 = extra[b * 512 + t];
        float a1 = extra[b * 512 + 256 + t];
        e[t] = a0; e[t + 256] = a1;
        red[t] = a0 + a1; red2[t] = a0 * a0 + a1 * a1;
        __syncthreads();
        for (int off = 128; off; off >>= 1) {
            if (t < off) { red[t] += red[t + off]; red2[t] += red2[t + off]; }
            __syncthreads();
        }
        const float mean = red[0] * (1.0f / 512.0f);
        const float var  = red2[0] * (1.0f / 512.0f) - mean * mean;
        const float rs   = rsqrtf(var + 1e-5f);
        e[t]       = (e[t]       - mean) * rs * ln2_g[t]       + ln2_b[t];
        e[t + 256] = (e[t + 256] - mean) * rs * ln2_g[t + 256] + ln2_b[t + 256];
        __syncthreads();
        {   // vrow[d] = sum_i e[i]*Wkv[i,64+d], split over 4 i-parts
            const int d = t & 63, pt = t >> 6;
            float acc = 0.0f;
            for (int i = pt * 128; i < pt * 128 + 128; ++i)
                acc += e[i] * Wkv[i * 128 + 64 + d];
            vpart[t] = acc;
        }
        __syncthreads();
        if (t < 64) vrow[t] = vpart[t] + vpart[t + 64] + vpart[t + 128] + vpart[t + 192];
        __syncthreads();
        {   // partial over i in [part*128, part*128+128), 4-way ILP
            const int i0 = part * 128;
            float a0_ = 0.f, a1_ = 0.f, a2_ = 0.f, a3_ = 0.f;
            for (int i = i0; i < i0 + 128; i += 4) {
                a0_ += vrow[i & 63]       * Wout[(i)     * 256 + t];
                a1_ += vrow[(i + 1) & 63] * Wout[(i + 1) * 256 + t];
                a2_ += vrow[(i + 2) & 63] * Wout[(i + 2) * 256 + t];
                a3_ += vrow[(i + 3) & 63] * Wout[(i + 3) * 256 + t];
            }
            attn_part[part * 4096 + b * 256 + t] = (a0_ + a1_) + (a2_ + a3_);
        }
    } else {
        __shared__ float tile[64][65];
        int id = blockIdx.x - 64;
        const float* src; u16* dst; int Rr, Cc, tr, tc;
        if (id < 64) { src = W1; dst = w1t; Rr = 256; Cc = 1024; tr = id >> 4; tc = id & 15; }
        else { id -= 64; src = W2; dst = w2t; Rr = 512; Cc = 256; tr = id >> 2; tc = id & 3; }
        const int rl = t >> 6, col = t & 63;
#pragma unroll
        for (int i = 0; i < 16; ++i) {
            int r = i * 4 + rl;
            tile[r][col] = src[(size_t)(tr * 64 + r) * Cc + tc * 64 + col];
        }
        __syncthreads();
        const int n_local = t & 63, cgrp = t >> 6;
        const int n = tc * 64 + n_local;
        const int rowmul = Rr * 16;
#pragma unroll
        for (int run = 0; run < 2; ++run) {
            int cl0 = cgrp * 16 + run * 8;
            int cc0 = tr * 64 + cl0;
            short8 w;
#pragma unroll
            for (int e2 = 0; e2 < 8; ++e2)
                w[e2] = (short)f2bf(tile[cl0 + e2][n_local]);
            size_t idx = (size_t)(n >> 4) * rowmul + (size_t)(cc0 >> 5) * 512
                       + (n & 15) * 32 + (cc0 & 31);
            *(short8*)(dst + idx) = w;
        }
    }
}

// ---------------------------------------------------------------------------
// Main: 64 positions per block (1024 blocks), 4 waves, 3 blocks/CU target.
// LDS: xs 64x256 bf16 (32 KiB), val[2] 64x64 bf16 (2x8 KiB, red overlaid).
// LDS swizzle: 16B-chunk phys = logicalChunk ^ (row & 7).
// ---------------------------------------------------------------------------
__global__ void __launch_bounds__(256, 3) main_kernel(
    const float* __restrict__ cnn,      // (16,256,64,64)
    const float* __restrict__ ln1_g,
    const float* __restrict__ ln1_b,
    const u16*  __restrict__ w1t,       // frag-tiled (Rr=256)
    const u16*  __restrict__ w2t,       // frag-tiled (Rr=512)
    const float* __restrict__ attn_part,// (4,16,256)
    float* __restrict__ out)            // (16,256,64,64)
{
    __shared__ u16 xs[64 * 256];     // 32 KiB
    __shared__ u16 val[2][64 * 64];  // 2 x 8 KiB (val[0] head doubles as red[])
    float* red = (float*)val;

    const int t  = threadIdx.x;
    const int b  = blockIdx.x >> 6;
    const int p0 = (blockIdx.x & 63) << 6;
    const int p  = t & 63;
    const int q  = t >> 6;          // wave id
    const int l15 = p & 15;
    const int lg  = p >> 4;
    const int wlane = l15 * 32 + lg * 8;   // u16 offset inside a 1KiB fragment

    // ---- GEMM1 weight prefetch registers (one chunk ahead) ----
    short8 wx[8], wg[8];
#define PREFETCH_W1(c_) do {                                                     \
        const int r16x = (c_) * 4 + q;                                           \
        const int r16g = 32 + (c_) * 4 + q;                                      \
        _Pragma("unroll")                                                        \
        for (int ks = 0; ks < 8; ++ks) {                                         \
            wx[ks] = *(const short8*)(w1t + (size_t)(r16x * 8 + ks) * 512 + wlane); \
            wg[ks] = *(const short8*)(w1t + (size_t)(r16g * 8 + ks) * 512 + wlane); \
        }                                                                        \
    } while (0)

    // ---- load cnn (coalesced along p) + LN stats ----
    const float* cb = cnn + (size_t)b * CDIM * HW + p0 + p;
    {
        float v[64];
        float s = 0.0f, s2 = 0.0f;
#pragma unroll
        for (int i = 0; i < 64; ++i) {
            float x = cb[(size_t)(q * 64 + i) * HW];
            v[i] = x; s += x; s2 += x * x;
        }
        red[q * 64 + p] = s;
        red[256 + q * 64 + p] = s2;
        BAR();
        if (t < 64) {
            float ss = red[t] + red[64 + t] + red[128 + t] + red[192 + t];
            float sq = red[256 + t] + red[320 + t] + red[384 + t] + red[448 + t];
            float mean = ss * (1.0f / 256.0f);
            float var  = sq * (1.0f / 256.0f) - mean * mean;
            red[512 + t] = mean;
            red[576 + t] = rsqrtf(var + 1e-5f);
        }
        BAR();
        // normalize + bf16 pack + XOR-swizzled b128 LDS writes
        const float mean = red[512 + p], rs = red[576 + p];
#pragma unroll
        for (int ic = 0; ic < 8; ++ic) {
            u32x4 w;
#pragma unroll
            for (int e2 = 0; e2 < 4; ++e2) {
                int c = q * 64 + ic * 8 + e2 * 2;
                float x0 = (v[ic * 8 + e2 * 2]     - mean) * rs * ln1_g[c]     + ln1_b[c];
                float x1 = (v[ic * 8 + e2 * 2 + 1] - mean) * rs * ln1_g[c + 1] + ln1_b[c + 1];
                w[e2] = cvtpk_bf16(x0, x1);
            }
            int phys = (q * 8 + ic) ^ (p & 7);
            *(u32x4*)((char*)xs + p * 512 + phys * 16) = w;
        }
    }   // v[] dies here — keeps peak regs under the 3-wave budget
    PREFETCH_W1(0);   // issued before the BAR -> in flight across it
    BAR();            // xs ready; all red reads done (val[0] now writable)

    f32x4 acc2[4][4];
#pragma unroll
    for (int n = 0; n < 4; ++n)
#pragma unroll
        for (int m = 0; m < 4; ++m)
            acc2[n][m] = (f32x4){0.0f, 0.0f, 0.0f, 0.0f};

    u32 pk[4][2];   // packed silu output: [m][pair] — 16 FFI values / lane

    // GEMM1C: consume prefetched wx/wg. Swapped operands: D col(l15)=position
    // tile m, D rows(lg*4+j)=FFI. silu folded into pk.
#define GEMM1C() do {                                                            \
        f32x4 axh[4], ag[4];                                                     \
        _Pragma("unroll")                                                        \
        for (int m = 0; m < 4; ++m) {                                            \
            axh[m] = (f32x4){0.0f, 0.0f, 0.0f, 0.0f};                            \
            ag[m]  = (f32x4){0.0f, 0.0f, 0.0f, 0.0f};                            \
        }                                                                        \
        _Pragma("unroll")                                                        \
        for (int ks = 0; ks < 8; ++ks) {                                         \
            short8 a_[4];                                                        \
            _Pragma("unroll")                                                    \
            for (int m = 0; m < 4; ++m) {                                        \
                int row = m * 16 + l15;                                          \
                int ph  = (ks * 4 + lg) ^ (row & 7);                             \
                a_[m] = *(const short8*)((const char*)xs + row * 512 + ph * 16); \
            }                                                                    \
            _Pragma("unroll")                                                    \
            for (int m = 0; m < 4; ++m) {                                        \
                axh[m] = __builtin_amdgcn_mfma_f32_16x16x32_bf16(wx[ks], a_[m], axh[m], 0, 0, 0); \
                ag[m]  = __builtin_amdgcn_mfma_f32_16x16x32_bf16(wg[ks], a_[m], ag[m], 0, 0, 0);  \
            }                                                                    \
        }                                                                        \
        _Pragma("unroll")                                                        \
        for (int m = 0; m < 4; ++m) {                                            \
            float sv[4];                                                         \
            _Pragma("unroll")                                                    \
            for (int j = 0; j < 4; ++j) {                                        \
                float g = ag[m][j];                                              \
                sv[j] = axh[m][j] * g * __builtin_amdgcn_rcpf(1.0f + __expf(-g)); \
            }                                                                    \
            pk[m][0] = cvtpk_bf16(sv[0], sv[1]);                                 \
            pk[m][1] = cvtpk_bf16(sv[2], sv[3]);                                 \
        }                                                                        \
    } while (0)

    // conflict-free 8B val writes: row=position, FFI-local col = q*16+lg*4
#define VALWRITE(dst_) do {                                                      \
        _Pragma("unroll")                                                        \
        for (int m = 0; m < 4; ++m) {                                            \
            int row = m * 16 + l15;                                              \
            int ph  = (q * 2 + (lg >> 1)) ^ (row & 7);                           \
            *(u32x2*)((char*)(dst_) + row * 128 + ph * 16 + (lg & 1) * 8) =      \
                (u32x2){pk[m][0], pk[m][1]};                                     \
        }                                                                        \
    } while (0)

    // GEMM2(chunk): wave q owns out-channels [q*64, +64); K = 64 FFI of chunk
#define GEMM2(c_, src_) do {                                                     \
        _Pragma("unroll")                                                        \
        for (int ks = 0; ks < 2; ++ks) {                                         \
            short8 a2[4], b2[4];                                                 \
            _Pragma("unroll")                                                    \
            for (int m = 0; m < 4; ++m) {                                        \
                int row = m * 16 + l15;                                          \
                int ph  = (ks * 4 + lg) ^ (row & 7);                             \
                a2[m] = *(const short8*)((const char*)(src_) + row * 128 + ph * 16); \
            }                                                                    \
            _Pragma("unroll")                                                    \
            for (int n = 0; n < 4; ++n)                                          \
                b2[n] = *(const short8*)(w2t + (size_t)((q * 4 + n) * 16 + (c_) * 2 + ks) * 512 + wlane); \
            _Pragma("unroll")                                                    \
            for (int n = 0; n < 4; ++n)                                          \
            _Pragma("unroll")                                                    \
            for (int m = 0; m < 4; ++m)                                          \
                acc2[n][m] = __builtin_amdgcn_mfma_f32_16x16x32_bf16(a2[m], b2[n], acc2[n][m], 0, 0, 0); \
        }                                                                        \
    } while (0)

    GEMM1C();          // chunk 0
    PREFETCH_W1(1);    // issued BEFORE the barrier -> in flight across it
    VALWRITE(val[0]);
    BAR();
#pragma unroll
    for (int c = 0; c < 8; ++c) {
        if (c < 7) GEMM1C();            // chunk c+1: weights already in regs
        if (c < 6) PREFETCH_W1(c + 2);  // issue before this chunk's barrier
        GEMM2(c, val[c & 1]);
        if (c < 7) {
            VALWRITE(val[(c + 1) & 1]); // other buffer: readers done at last BAR
            BAR();
        }
    }

    // ---- epilogue: + attn row (4 partials), f32x4 stores ----
    float* ob = out + (size_t)b * CDIM * HW;
#pragma unroll
    for (int n = 0; n < 4; ++n) {
        int cg = b * 256 + q * 64 + n * 16 + l15;
        float att = (attn_part[cg] + attn_part[4096 + cg])
                  + (attn_part[8192 + cg] + attn_part[12288 + cg]);
        int c = q * 64 + n * 16 + l15;
#pragma unroll
        for (int m = 0; m < 4; ++m) {
            f32x4 r = acc2[n][m];
            r[0] += att; r[1] += att; r[2] += att; r[3] += att;
            *(f32x4*)(ob + (size_t)c * HW + p0 + m * 16 + lg * 4) = r;
        }
    }
#undef PREFETCH_W1
#undef GEMM1C
#undef GEMM2
#undef VALWRITE
}

// ---------------------------------------------------------------------------
extern "C" void kernel_launch(void* const* d_in, const int* in_sizes, int n_in,
                              void* d_out, int out_size, void* d_ws, size_t ws_size,
                              hipStream_t stream) {
    const float* cnn   = (const float*)d_in[0];
    const float* extra = (const float*)d_in[1];
    const float* ln1_g = (const float*)d_in[2];
    const float* ln1_b = (const float*)d_in[3];
    const float* ln2_g = (const float*)d_in[4];
    const float* ln2_b = (const float*)d_in[5];
    // d_in[6] = Wq — provably unused
    const float* Wkv   = (const float*)d_in[7];
    const float* Wout  = (const float*)d_in[8];
    const float* W1    = (const float*)d_in[9];
    const float* W2    = (const float*)d_in[10];
    float* out = (float*)d_out;

    char* ws = (char*)d_ws;
    float* attn_part = (float*)ws;                         // 64 KiB (4x16x256)
    u16*   w1t       = (u16*)(ws + 64 * 1024);             // 512 KiB
    u16*   w2t       = (u16*)(ws + 64 * 1024 + 512 * 1024);// 256 KiB

    prep_kernel<<<160, 256, 0, stream>>>(extra, ln2_g, ln2_b, Wkv, Wout, W1, W2,
                                         attn_part, w1t, w2t);
    main_kernel<<<BATCH * 64, 256, 0, stream>>>(cnn, ln1_g, ln1_b, w1t, w2t,
                                                attn_part, out);
}

// Round 10
// 128.364 us; speedup vs baseline: 1.0723x; 1.0723x over previous
//
#include <hip/hip_runtime.h>
#include <math.h>

// ===========================================================================
// CrossAttentionLayer — collapsed attention + bf16-MFMA SwiGLU FF.
//
// kv is broadcast over j => softmax exactly uniform => attention out = v_row,
// independent of q (Wq unused):
//   attn_out[b,c] = sum_i vrow[b, i&63] * Wout[i,c],
//   vrow[b,:] = (LN(extra[b]) @ Wkv)[64:128].
// Per position: x = LN_C(cnn); h = x@W1; ff = (silu(h[512:])*h[:512])@W2;
//   out[b,c,p] = attn_out[b,c] + ff[p,c]
//
// Round-10: 3 blocks/CU WITHOUT spills. R9 failed because the 64-reg W1
// prefetch made natural need (180) exceed the 170-reg 3-wave budget -> the
// (256,3) cap forced ~30 regs of hot-loop spill (WRITE_SIZE 67->170MB).
// Fix: HALVED prefetch depth wx[4]/wg[4] (32 regs), re-issued at half-chunk
// granularity inside GEMM1; natural need ~150 incl. 64 AGPR <= 170.
// Rationale: measured 84us = SUM of pipe floors (MFMA 25 + LDS 20 + L2 22 +
// VALU 17) -> zero cross-pipe overlap from 2 phase-locked waves/SIMD; a 3rd
// resident block (independent barrier group) is the decorrelator, and it
// also hides the half-boundary vmcnt stall (m114 wave-level overlap).
// ===========================================================================

#define BATCH 16
#define CDIM  256
#define HW    4096

using short8 = __attribute__((ext_vector_type(8))) short;
using f32x4  = __attribute__((ext_vector_type(4))) float;
using u32x2  = __attribute__((ext_vector_type(2))) unsigned int;
using u32x4  = __attribute__((ext_vector_type(4))) unsigned int;
typedef unsigned int   u32;
typedef unsigned short u16;

__device__ __forceinline__ u16 f2bf(float f) {
    u32 u = __float_as_uint(f);
    u += 0x7fffu + ((u >> 16) & 1u);   // round-nearest-even
    return (u16)(u >> 16);
}

__device__ __forceinline__ u32 cvtpk_bf16(float lo, float hi) {
    u32 r;
    asm("v_cvt_pk_bf16_f32 %0, %1, %2" : "=v"(r) : "v"(lo), "v"(hi));
    return r;
}

// lgkm drain (LDS visibility) + barrier; NO vmcnt drain (global weight loads
// stay in flight across the barrier). "memory" pins compile-time order.
#define BAR() asm volatile("s_waitcnt lgkmcnt(0)\n\ts_barrier" ::: "memory")

// ---------------------------------------------------------------------------
// Prep (R8 form): blocks 0..63 attn-row partials (4x parallel); 64..127
// W1->frag-tiled; 128..159 W2->frag-tiled. Fragment-tiled index: element
// (row n, col cc) at (n>>4)*(Rr*16)+(cc>>5)*512+(n&15)*32+(cc&31).
// ---------------------------------------------------------------------------
__global__ void prep_kernel(const float* __restrict__ extra,
                            const float* __restrict__ ln2_g,
                            const float* __restrict__ ln2_b,
                            const float* __restrict__ Wkv,
                            const float* __restrict__ Wout,
                            const float* __restrict__ W1,
                            const float* __restrict__ W2,
                            float* __restrict__ attn_part,   // (4,16,256)
                            u16* __restrict__ w1t,
                            u16* __restrict__ w2t)
{
    const int t = threadIdx.x;
    if (blockIdx.x < 64) {
        __shared__ float e[512];
        __shared__ float red[256], red2[256];
        __shared__ float vpart[256];
        __shared__ float vrow[64];
        const int b    = blockIdx.x >> 2;
        const int part = blockIdx.x & 3;
        float a0 = extra[b * 512 + t];
        float a1 = extra[b * 512 + 256 + t];
        e[t] = a0; e[t + 256] = a1;
        red[t] = a0 + a1; red2[t] = a0 * a0 + a1 * a1;
        __syncthreads();
        for (int off = 128; off; off >>= 1) {
            if (t < off) { red[t] += red[t + off]; red2[t] += red2[t + off]; }
            __syncthreads();
        }
        const float mean = red[0] * (1.0f / 512.0f);
        const float var  = red2[0] * (1.0f / 512.0f) - mean * mean;
        const float rs   = rsqrtf(var + 1e-5f);
        e[t]       = (e[t]       - mean) * rs * ln2_g[t]       + ln2_b[t];
        e[t + 256] = (e[t + 256] - mean) * rs * ln2_g[t + 256] + ln2_b[t + 256];
        __syncthreads();
        {   // vrow[d] = sum_i e[i]*Wkv[i,64+d], split over 4 i-parts
            const int d = t & 63, pt = t >> 6;
            float acc = 0.0f;
            for (int i = pt * 128; i < pt * 128 + 128; ++i)
                acc += e[i] * Wkv[i * 128 + 64 + d];
            vpart[t] = acc;
        }
        __syncthreads();
        if (t < 64) vrow[t] = vpart[t] + vpart[t + 64] + vpart[t + 128] + vpart[t + 192];
        __syncthreads();
        {   // partial over i in [part*128, part*128+128), 4-way ILP
            const int i0 = part * 128;
            float a0_ = 0.f, a1_ = 0.f, a2_ = 0.f, a3_ = 0.f;
            for (int i = i0; i < i0 + 128; i += 4) {
                a0_ += vrow[i & 63]       * Wout[(i)     * 256 + t];
                a1_ += vrow[(i + 1) & 63] * Wout[(i + 1) * 256 + t];
                a2_ += vrow[(i + 2) & 63] * Wout[(i + 2) * 256 + t];
                a3_ += vrow[(i + 3) & 63] * Wout[(i + 3) * 256 + t];
            }
            attn_part[part * 4096 + b * 256 + t] = (a0_ + a1_) + (a2_ + a3_);
        }
    } else {
        __shared__ float tile[64][65];
        int id = blockIdx.x - 64;
        const float* src; u16* dst; int Rr, Cc, tr, tc;
        if (id < 64) { src = W1; dst = w1t; Rr = 256; Cc = 1024; tr = id >> 4; tc = id & 15; }
        else { id -= 64; src = W2; dst = w2t; Rr = 512; Cc = 256; tr = id >> 2; tc = id & 3; }
        const int rl = t >> 6, col = t & 63;
#pragma unroll
        for (int i = 0; i < 16; ++i) {
            int r = i * 4 + rl;
            tile[r][col] = src[(size_t)(tr * 64 + r) * Cc + tc * 64 + col];
        }
        __syncthreads();
        const int n_local = t & 63, cgrp = t >> 6;
        const int n = tc * 64 + n_local;
        const int rowmul = Rr * 16;
#pragma unroll
        for (int run = 0; run < 2; ++run) {
            int cl0 = cgrp * 16 + run * 8;
            int cc0 = tr * 64 + cl0;
            short8 w;
#pragma unroll
            for (int e2 = 0; e2 < 8; ++e2)
                w[e2] = (short)f2bf(tile[cl0 + e2][n_local]);
            size_t idx = (size_t)(n >> 4) * rowmul + (size_t)(cc0 >> 5) * 512
                       + (n & 15) * 32 + (cc0 & 31);
            *(short8*)(dst + idx) = w;
        }
    }
}

// ---------------------------------------------------------------------------
// Main: 64 positions per block (1024 blocks), 4 waves, 3 blocks/CU.
// LDS: xs 64x256 bf16 (32 KiB), val[2] 64x64 bf16 (2x8 KiB, red overlaid).
// LDS swizzle: 16B-chunk phys = logicalChunk ^ (row & 7).
// ---------------------------------------------------------------------------
__global__ void __launch_bounds__(256, 3) main_kernel(
    const float* __restrict__ cnn,      // (16,256,64,64)
    const float* __restrict__ ln1_g,
    const float* __restrict__ ln1_b,
    const u16*  __restrict__ w1t,       // frag-tiled (Rr=256)
    const u16*  __restrict__ w2t,       // frag-tiled (Rr=512)
    const float* __restrict__ attn_part,// (4,16,256)
    float* __restrict__ out)            // (16,256,64,64)
{
    __shared__ u16 xs[64 * 256];     // 32 KiB
    __shared__ u16 val[2][64 * 64];  // 2 x 8 KiB (val[0] head doubles as red[])
    float* red = (float*)val;

    const int t  = threadIdx.x;
    const int b  = blockIdx.x >> 6;
    const int p0 = (blockIdx.x & 63) << 6;
    const int p  = t & 63;
    const int q  = t >> 6;          // wave id
    const int l15 = p & 15;
    const int lg  = p >> 4;
    const int wlane = l15 * 32 + lg * 8;   // u16 offset inside a 1KiB fragment

    // ---- GEMM1 weight prefetch registers: HALF-chunk depth (32 VGPR) ----
    short8 wx[4], wg[4];
#define PREFETCH_W1(c_, h_) do {                                                 \
        const int r16x = (c_) * 4 + q;                                           \
        const int r16g = 32 + (c_) * 4 + q;                                      \
        _Pragma("unroll")                                                        \
        for (int k4 = 0; k4 < 4; ++k4) {                                         \
            wx[k4] = *(const short8*)(w1t + (size_t)(r16x * 8 + (h_) * 4 + k4) * 512 + wlane); \
            wg[k4] = *(const short8*)(w1t + (size_t)(r16g * 8 + (h_) * 4 + k4) * 512 + wlane); \
        }                                                                        \
    } while (0)

    // ---- load cnn (coalesced along p) + LN stats ----
    const float* cb = cnn + (size_t)b * CDIM * HW + p0 + p;
    {
        float v[64];
        float s = 0.0f, s2 = 0.0f;
#pragma unroll
        for (int i = 0; i < 64; ++i) {
            float x = cb[(size_t)(q * 64 + i) * HW];
            v[i] = x; s += x; s2 += x * x;
        }
        red[q * 64 + p] = s;
        red[256 + q * 64 + p] = s2;
        BAR();
        if (t < 64) {
            float ss = red[t] + red[64 + t] + red[128 + t] + red[192 + t];
            float sq = red[256 + t] + red[320 + t] + red[384 + t] + red[448 + t];
            float mean = ss * (1.0f / 256.0f);
            float var  = sq * (1.0f / 256.0f) - mean * mean;
            red[512 + t] = mean;
            red[576 + t] = rsqrtf(var + 1e-5f);
        }
        BAR();
        // normalize + bf16 pack + XOR-swizzled b128 LDS writes
        const float mean = red[512 + p], rs = red[576 + p];
#pragma unroll
        for (int ic = 0; ic < 8; ++ic) {
            u32x4 w;
#pragma unroll
            for (int e2 = 0; e2 < 4; ++e2) {
                int c = q * 64 + ic * 8 + e2 * 2;
                float x0 = (v[ic * 8 + e2 * 2]     - mean) * rs * ln1_g[c]     + ln1_b[c];
                float x1 = (v[ic * 8 + e2 * 2 + 1] - mean) * rs * ln1_g[c + 1] + ln1_b[c + 1];
                w[e2] = cvtpk_bf16(x0, x1);
            }
            int phys = (q * 8 + ic) ^ (p & 7);
            *(u32x4*)((char*)xs + p * 512 + phys * 16) = w;
        }
    }   // v[] dies here — keeps peak regs under the 3-wave budget
    PREFETCH_W1(0, 0);   // issued before the BAR -> in flight across it
    BAR();               // xs ready; all red reads done (val[0] now writable)

    f32x4 acc2[4][4];
#pragma unroll
    for (int n = 0; n < 4; ++n)
#pragma unroll
        for (int m = 0; m < 4; ++m)
            acc2[n][m] = (f32x4){0.0f, 0.0f, 0.0f, 0.0f};

    u32 pk[4][2];   // packed silu output: [m][pair] — 16 FFI values / lane

    // GEMM1 for chunk c_: two halves; wx/wg must hold (c_,h0) at entry.
    // Re-issues prefetch of (c_,h1) between halves and (c_+1,h0) after
    // (loads fly across the chunk barrier). Swapped operands: D col(l15)=
    // position tile m, D rows(lg*4+j)=FFI. silu folded into pk.
#define GEMM1SPLIT(c_) do {                                                      \
        f32x4 axh[4], ag[4];                                                     \
        _Pragma("unroll")                                                        \
        for (int m = 0; m < 4; ++m) {                                            \
            axh[m] = (f32x4){0.0f, 0.0f, 0.0f, 0.0f};                            \
            ag[m]  = (f32x4){0.0f, 0.0f, 0.0f, 0.0f};                            \
        }                                                                        \
        _Pragma("unroll")                                                        \
        for (int h = 0; h < 2; ++h) {                                            \
            _Pragma("unroll")                                                    \
            for (int k4 = 0; k4 < 4; ++k4) {                                     \
                int ks = h * 4 + k4;                                             \
                short8 a_[4];                                                    \
                _Pragma("unroll")                                                \
                for (int m = 0; m < 4; ++m) {                                    \
                    int row = m * 16 + l15;                                      \
                    int ph  = (ks * 4 + lg) ^ (row & 7);                         \
                    a_[m] = *(const short8*)((const char*)xs + row * 512 + ph * 16); \
                }                                                                \
                _Pragma("unroll")                                                \
                for (int m = 0; m < 4; ++m) {                                    \
                    axh[m] = __builtin_amdgcn_mfma_f32_16x16x32_bf16(wx[k4], a_[m], axh[m], 0, 0, 0); \
                    ag[m]  = __builtin_amdgcn_mfma_f32_16x16x32_bf16(wg[k4], a_[m], ag[m], 0, 0, 0);  \
                }                                                                \
            }                                                                    \
            if (h == 0) PREFETCH_W1(c_, 1);                                      \
            else if ((c_) < 7) PREFETCH_W1((c_) + 1, 0);                         \
        }                                                                        \
        _Pragma("unroll")                                                        \
        for (int m = 0; m < 4; ++m) {                                            \
            float sv[4];                                                         \
            _Pragma("unroll")                                                    \
            for (int j = 0; j < 4; ++j) {                                        \
                float g = ag[m][j];                                              \
                sv[j] = axh[m][j] * g * __builtin_amdgcn_rcpf(1.0f + __expf(-g)); \
            }                                                                    \
            pk[m][0] = cvtpk_bf16(sv[0], sv[1]);                                 \
            pk[m][1] = cvtpk_bf16(sv[2], sv[3]);                                 \
        }                                                                        \
    } while (0)

    // conflict-free 8B val writes: row=position, FFI-local col = q*16+lg*4
#define VALWRITE(dst_) do {                                                      \
        _Pragma("unroll")                                                        \
        for (int m = 0; m < 4; ++m) {                                            \
            int row = m * 16 + l15;                                              \
            int ph  = (q * 2 + (lg >> 1)) ^ (row & 7);                           \
            *(u32x2*)((char*)(dst_) + row * 128 + ph * 16 + (lg & 1) * 8) =      \
                (u32x2){pk[m][0], pk[m][1]};                                     \
        }                                                                        \
    } while (0)

    // GEMM2(chunk): wave q owns out-channels [q*64, +64); K = 64 FFI of chunk
#define GEMM2(c_, src_) do {                                                     \
        _Pragma("unroll")                                                        \
        for (int ks = 0; ks < 2; ++ks) {                                         \
            short8 a2[4], b2[4];                                                 \
            _Pragma("unroll")                                                    \
            for (int m = 0; m < 4; ++m) {                                        \
                int row = m * 16 + l15;                                          \
                int ph  = (ks * 4 + lg) ^ (row & 7);                             \
                a2[m] = *(const short8*)((const char*)(src_) + row * 128 + ph * 16); \
            }                                                                    \
            _Pragma("unroll")                                                    \
            for (int n = 0; n < 4; ++n)                                          \
                b2[n] = *(const short8*)(w2t + (size_t)((q * 4 + n) * 16 + (c_) * 2 + ks) * 512 + wlane); \
            _Pragma("unroll")                                                    \
            for (int n = 0; n < 4; ++n)                                          \
            _Pragma("unroll")                                                    \
            for (int m = 0; m < 4; ++m)                                          \
                acc2[n][m] = __builtin_amdgcn_mfma_f32_16x16x32_bf16(a2[m], b2[n], acc2[n][m], 0, 0, 0); \
        }                                                                        \
    } while (0)

    GEMM1SPLIT(0);     // chunk 0 (h0 prefetched above; h1 + (1,h0) inside)
    VALWRITE(val[0]);
    BAR();
#pragma unroll
    for (int c = 0; c < 8; ++c) {
        if (c < 7) GEMM1SPLIT(c + 1);   // chunk c+1; prefetches re-issued inside
        GEMM2(c, val[c & 1]);
        if (c < 7) {
            VALWRITE(val[(c + 1) & 1]); // other buffer: readers done at last BAR
            BAR();
        }
    }

    // ---- epilogue: + attn row (4 partials), f32x4 stores ----
    float* ob = out + (size_t)b * CDIM * HW;
#pragma unroll
    for (int n = 0; n < 4; ++n) {
        int cg = b * 256 + q * 64 + n * 16 + l15;
        float att = (attn_part[cg] + attn_part[4096 + cg])
                  + (attn_part[8192 + cg] + attn_part[12288 + cg]);
        int c = q * 64 + n * 16 + l15;
#pragma unroll
        for (int m = 0; m < 4; ++m) {
            f32x4 r = acc2[n][m];
            r[0] += att; r[1] += att; r[2] += att; r[3] += att;
            *(f32x4*)(ob + (size_t)c * HW + p0 + m * 16 + lg * 4) = r;
        }
    }
#undef PREFETCH_W1
#undef GEMM1SPLIT
#undef GEMM2
#undef VALWRITE
}

// ---------------------------------------------------------------------------
extern "C" void kernel_launch(void* const* d_in, const int* in_sizes, int n_in,
                              void* d_out, int out_size, void* d_ws, size_t ws_size,
                              hipStream_t stream) {
    const float* cnn   = (const float*)d_in[0];
    const float* extra = (const float*)d_in[1];
    const float* ln1_g = (const float*)d_in[2];
    const float* ln1_b = (const float*)d_in[3];
    const float* ln2_g = (const float*)d_in[4];
    const float* ln2_b = (const float*)d_in[5];
    // d_in[6] = Wq — provably unused
    const float* Wkv   = (const float*)d_in[7];
    const float* Wout  = (const float*)d_in[8];
    const float* W1    = (const float*)d_in[9];
    const float* W2    = (const float*)d_in[10];
    float* out = (float*)d_out;

    char* ws = (char*)d_ws;
    float* attn_part = (float*)ws;                         // 64 KiB (4x16x256)
    u16*   w1t       = (u16*)(ws + 64 * 1024);             // 512 KiB
    u16*   w2t       = (u16*)(ws + 64 * 1024 + 512 * 1024);// 256 KiB

    prep_kernel<<<160, 256, 0, stream>>>(extra, ln2_g, ln2_b, Wkv, Wout, W1, W2,
                                         attn_part, w1t, w2t);
    main_kernel<<<BATCH * 64, 256, 0, stream>>>(cnn, ln1_g, ln1_b, w1t, w2t,
                                                attn_part, out);
}

// Round 11
// 81.432 us; speedup vs baseline: 1.6903x; 1.5763x over previous
//
#include <hip/hip_runtime.h>
#include <math.h>

// ===========================================================================
// CrossAttentionLayer — collapsed attention + bf16-MFMA SwiGLU FF.
//
// kv is broadcast over j => softmax exactly uniform => attention out = v_row,
// independent of q (Wq unused):
//   attn_out[b,c] = sum_i vrow[b, i&63] * Wout[i,c],
//   vrow[b,:] = (LN(extra[b]) @ Wkv)[64:128].
// Per position: x = LN_C(cnn); h = x@W1; ff = (silu(h[512:])*h[:512])@W2;
//   out[b,c,p] = attn_out[b,c] + ff[p,c]
//
// Round-11 = R7 main VERBATIM (best measured: 84us; entry-time full-depth
// W1 register prefetch, inline W2 loads, no setprio, launch_bounds(256,2))
// + prep vpart loop 4-way ILP (was a serial 128-iter dependent FMA chain
// with L2-latency loads ~16us on the prep critical path).
// Dead ends measured: 3 blocks/CU (R3/R9/R10 — compiler hoists prefetches,
// cap forces spills, WRITE_SIZE balloons), two-stream (R6, spills),
// w2f prefetch + setprio (R8, neutral-to-negative).
// ===========================================================================

#define BATCH 16
#define CDIM  256
#define HW    4096

using short8 = __attribute__((ext_vector_type(8))) short;
using f32x4  = __attribute__((ext_vector_type(4))) float;
using u32x2  = __attribute__((ext_vector_type(2))) unsigned int;
using u32x4  = __attribute__((ext_vector_type(4))) unsigned int;
typedef unsigned int   u32;
typedef unsigned short u16;

__device__ __forceinline__ u16 f2bf(float f) {
    u32 u = __float_as_uint(f);
    u += 0x7fffu + ((u >> 16) & 1u);   // round-nearest-even
    return (u16)(u >> 16);
}

__device__ __forceinline__ u32 cvtpk_bf16(float lo, float hi) {
    u32 r;
    asm("v_cvt_pk_bf16_f32 %0, %1, %2" : "=v"(r) : "v"(lo), "v"(hi));
    return r;
}

// lgkm drain (LDS visibility) + barrier; NO vmcnt drain (global weight loads
// stay in flight across the barrier). "memory" pins compile-time order.
#define BAR() asm volatile("s_waitcnt lgkmcnt(0)\n\ts_barrier" ::: "memory")

// ---------------------------------------------------------------------------
// Prep: blocks 0..63   -> attn-row partials (part=id&3 over i-range of 128)
//       blocks 64..127 -> W1 (256x1024) -> frag-tiled (Rr=256)
//       blocks 128..159-> W2 (512x256)  -> frag-tiled (Rr=512)
// Fragment-tiled index: element (row n, col cc) at
// (n>>4)*(Rr*16) + (cc>>5)*512 + (n&15)*32 + (cc&31); lane off l15*32+lg*8.
// ---------------------------------------------------------------------------
__global__ void prep_kernel(const float* __restrict__ extra,
                            const float* __restrict__ ln2_g,
                            const float* __restrict__ ln2_b,
                            const float* __restrict__ Wkv,
                            const float* __restrict__ Wout,
                            const float* __restrict__ W1,
                            const float* __restrict__ W2,
                            float* __restrict__ attn_part,   // (4,16,256)
                            u16* __restrict__ w1t,
                            u16* __restrict__ w2t)
{
    const int t = threadIdx.x;
    if (blockIdx.x < 64) {
        __shared__ float e[512];
        __shared__ float red[256], red2[256];
        __shared__ float vpart[256];
        __shared__ float vrow[64];
        const int b    = blockIdx.x >> 2;
        const int part = blockIdx.x & 3;
        float a0 = extra[b * 512 + t];
        float a1 = extra[b * 512 + 256 + t];
        e[t] = a0; e[t + 256] = a1;
        red[t] = a0 + a1; red2[t] = a0 * a0 + a1 * a1;
        __syncthreads();
        for (int off = 128; off; off >>= 1) {
            if (t < off) { red[t] += red[t + off]; red2[t] += red2[t + off]; }
            __syncthreads();
        }
        const float mean = red[0] * (1.0f / 512.0f);
        const float var  = red2[0] * (1.0f / 512.0f) - mean * mean;
        const float rs   = rsqrtf(var + 1e-5f);
        e[t]       = (e[t]       - mean) * rs * ln2_g[t]       + ln2_b[t];
        e[t + 256] = (e[t + 256] - mean) * rs * ln2_g[t + 256] + ln2_b[t + 256];
        __syncthreads();
        {   // vrow[d] = sum_i e[i]*Wkv[i,64+d]: 4 i-parts x 4-way ILP
            const int d = t & 63, pt = t >> 6;
            const int i0 = pt * 128;
            float c0 = 0.f, c1 = 0.f, c2 = 0.f, c3 = 0.f;
            for (int i = i0; i < i0 + 128; i += 4) {
                c0 += e[i]     * Wkv[(i)     * 128 + 64 + d];
                c1 += e[i + 1] * Wkv[(i + 1) * 128 + 64 + d];
                c2 += e[i + 2] * Wkv[(i + 2) * 128 + 64 + d];
                c3 += e[i + 3] * Wkv[(i + 3) * 128 + 64 + d];
            }
            vpart[t] = (c0 + c1) + (c2 + c3);
        }
        __syncthreads();
        if (t < 64) vrow[t] = vpart[t] + vpart[t + 64] + vpart[t + 128] + vpart[t + 192];
        __syncthreads();
        {   // partial over i in [part*128, part*128+128), 4-way ILP
            const int i0 = part * 128;
            float a0_ = 0.f, a1_ = 0.f, a2_ = 0.f, a3_ = 0.f;
            for (int i = i0; i < i0 + 128; i += 4) {
                a0_ += vrow[i & 63]       * Wout[(i)     * 256 + t];
                a1_ += vrow[(i + 1) & 63] * Wout[(i + 1) * 256 + t];
                a2_ += vrow[(i + 2) & 63] * Wout[(i + 2) * 256 + t];
                a3_ += vrow[(i + 3) & 63] * Wout[(i + 3) * 256 + t];
            }
            attn_part[part * 4096 + b * 256 + t] = (a0_ + a1_) + (a2_ + a3_);
        }
    } else {
        __shared__ float tile[64][65];
        int id = blockIdx.x - 64;
        const float* src; u16* dst; int Rr, Cc, tr, tc;
        if (id < 64) { src = W1; dst = w1t; Rr = 256; Cc = 1024; tr = id >> 4; tc = id & 15; }
        else { id -= 64; src = W2; dst = w2t; Rr = 512; Cc = 256; tr = id >> 2; tc = id & 3; }
        const int rl = t >> 6, col = t & 63;
#pragma unroll
        for (int i = 0; i < 16; ++i) {
            int r = i * 4 + rl;
            tile[r][col] = src[(size_t)(tr * 64 + r) * Cc + tc * 64 + col];
        }
        __syncthreads();
        const int n_local = t & 63, cgrp = t >> 6;
        const int n = tc * 64 + n_local;
        const int rowmul = Rr * 16;
#pragma unroll
        for (int run = 0; run < 2; ++run) {
            int cl0 = cgrp * 16 + run * 8;
            int cc0 = tr * 64 + cl0;
            short8 w;
#pragma unroll
            for (int e2 = 0; e2 < 8; ++e2)
                w[e2] = (short)f2bf(tile[cl0 + e2][n_local]);
            size_t idx = (size_t)(n >> 4) * rowmul + (size_t)(cc0 >> 5) * 512
                       + (n & 15) * 32 + (cc0 & 31);
            *(short8*)(dst + idx) = w;
        }
    }
}

// ---------------------------------------------------------------------------
// Main (R7 verbatim): 64 positions per block (1024 blocks), 4 waves,
// 2 blocks/CU. LDS: xs 64x256 bf16 (32 KiB), val[2] 64x64 bf16 (2x8 KiB,
// red overlaid). LDS swizzle: 16B-chunk phys = logicalChunk ^ (row & 7).
// ---------------------------------------------------------------------------
__global__ void __launch_bounds__(256, 2) main_kernel(
    const float* __restrict__ cnn,      // (16,256,64,64)
    const float* __restrict__ ln1_g,
    const float* __restrict__ ln1_b,
    const u16*  __restrict__ w1t,       // frag-tiled (Rr=256)
    const u16*  __restrict__ w2t,       // frag-tiled (Rr=512)
    const float* __restrict__ attn_part,// (4,16,256)
    float* __restrict__ out)            // (16,256,64,64)
{
    __shared__ u16 xs[64 * 256];     // 32 KiB
    __shared__ u16 val[2][64 * 64];  // 2 x 8 KiB (val[0] head doubles as red[])
    float* red = (float*)val;

    const int t  = threadIdx.x;
    const int b  = blockIdx.x >> 6;
    const int p0 = (blockIdx.x & 63) << 6;
    const int p  = t & 63;
    const int q  = t >> 6;          // wave id
    const int l15 = p & 15;
    const int lg  = p >> 4;
    const int wlane = l15 * 32 + lg * 8;   // u16 offset inside a 1KiB fragment

    // ---- GEMM1 weight prefetch registers (one full chunk ahead) ----
    short8 wx[8], wg[8];
#define PREFETCH_W1(c_) do {                                                     \
        const int r16x = (c_) * 4 + q;                                           \
        const int r16g = 32 + (c_) * 4 + q;                                      \
        _Pragma("unroll")                                                        \
        for (int ks = 0; ks < 8; ++ks) {                                         \
            wx[ks] = *(const short8*)(w1t + (size_t)(r16x * 8 + ks) * 512 + wlane); \
            wg[ks] = *(const short8*)(w1t + (size_t)(r16g * 8 + ks) * 512 + wlane); \
        }                                                                        \
    } while (0)

    PREFETCH_W1(0);   // issued at kernel entry — hidden under the prologue

    // ---- load cnn (coalesced along p) + LN stats ----
    const float* cb = cnn + (size_t)b * CDIM * HW + p0 + p;
    float v[64];
    float s = 0.0f, s2 = 0.0f;
#pragma unroll
    for (int i = 0; i < 64; ++i) {
        float x = cb[(size_t)(q * 64 + i) * HW];
        v[i] = x; s += x; s2 += x * x;
    }
    red[q * 64 + p] = s;
    red[256 + q * 64 + p] = s2;
    BAR();
    if (t < 64) {
        float ss = red[t] + red[64 + t] + red[128 + t] + red[192 + t];
        float sq = red[256 + t] + red[320 + t] + red[384 + t] + red[448 + t];
        float mean = ss * (1.0f / 256.0f);
        float var  = sq * (1.0f / 256.0f) - mean * mean;
        red[512 + t] = mean;
        red[576 + t] = rsqrtf(var + 1e-5f);
    }
    BAR();
    {   // normalize + bf16 pack + XOR-swizzled b128 LDS writes
        const float mean = red[512 + p], rs = red[576 + p];
#pragma unroll
        for (int ic = 0; ic < 8; ++ic) {
            u32x4 w;
#pragma unroll
            for (int e2 = 0; e2 < 4; ++e2) {
                int c = q * 64 + ic * 8 + e2 * 2;
                float x0 = (v[ic * 8 + e2 * 2]     - mean) * rs * ln1_g[c]     + ln1_b[c];
                float x1 = (v[ic * 8 + e2 * 2 + 1] - mean) * rs * ln1_g[c + 1] + ln1_b[c + 1];
                w[e2] = cvtpk_bf16(x0, x1);
            }
            int phys = (q * 8 + ic) ^ (p & 7);
            *(u32x4*)((char*)xs + p * 512 + phys * 16) = w;
        }
    }
    // epilogue attention row (sum of 4 partials) — load early, hides behind loop
    float att[4];
#pragma unroll
    for (int n = 0; n < 4; ++n) {
        int cg = b * 256 + q * 64 + n * 16 + l15;
        att[n] = (attn_part[cg] + attn_part[4096 + cg])
               + (attn_part[8192 + cg] + attn_part[12288 + cg]);
    }
    BAR();   // xs ready; all red reads done (val[0] now writable)

    f32x4 acc2[4][4];
#pragma unroll
    for (int n = 0; n < 4; ++n)
#pragma unroll
        for (int m = 0; m < 4; ++m)
            acc2[n][m] = (f32x4){0.0f, 0.0f, 0.0f, 0.0f};

    u32 pk[4][2];   // packed silu output: [m][pair] — 16 FFI values / lane

    // GEMM1C: consume prefetched wx/wg. Swapped operands: D col(l15)=position
    // tile m, D rows(lg*4+j)=FFI. silu folded into pk.
#define GEMM1C() do {                                                            \
        f32x4 axh[4], ag[4];                                                     \
        _Pragma("unroll")                                                        \
        for (int m = 0; m < 4; ++m) {                                            \
            axh[m] = (f32x4){0.0f, 0.0f, 0.0f, 0.0f};                            \
            ag[m]  = (f32x4){0.0f, 0.0f, 0.0f, 0.0f};                            \
        }                                                                        \
        _Pragma("unroll")                                                        \
        for (int ks = 0; ks < 8; ++ks) {                                         \
            short8 a_[4];                                                        \
            _Pragma("unroll")                                                    \
            for (int m = 0; m < 4; ++m) {                                        \
                int row = m * 16 + l15;                                          \
                int ph  = (ks * 4 + lg) ^ (row & 7);                             \
                a_[m] = *(const short8*)((const char*)xs + row * 512 + ph * 16); \
            }                                                                    \
            _Pragma("unroll")                                                    \
            for (int m = 0; m < 4; ++m) {                                        \
                axh[m] = __builtin_amdgcn_mfma_f32_16x16x32_bf16(wx[ks], a_[m], axh[m], 0, 0, 0); \
                ag[m]  = __builtin_amdgcn_mfma_f32_16x16x32_bf16(wg[ks], a_[m], ag[m], 0, 0, 0);  \
            }                                                                    \
        }                                                                        \
        _Pragma("unroll")                                                        \
        for (int m = 0; m < 4; ++m) {                                            \
            float sv[4];                                                         \
            _Pragma("unroll")                                                    \
            for (int j = 0; j < 4; ++j) {                                        \
                float g = ag[m][j];                                              \
                sv[j] = axh[m][j] * g * __builtin_amdgcn_rcpf(1.0f + __expf(-g)); \
            }                                                                    \
            pk[m][0] = cvtpk_bf16(sv[0], sv[1]);                                 \
            pk[m][1] = cvtpk_bf16(sv[2], sv[3]);                                 \
        }                                                                        \
    } while (0)

    // conflict-free 8B val writes: row=position, FFI-local col = q*16+lg*4
#define VALWRITE(dst_) do {                                                      \
        _Pragma("unroll")                                                        \
        for (int m = 0; m < 4; ++m) {                                            \
            int row = m * 16 + l15;                                              \
            int ph  = (q * 2 + (lg >> 1)) ^ (row & 7);                           \
            *(u32x2*)((char*)(dst_) + row * 128 + ph * 16 + (lg & 1) * 8) =      \
                (u32x2){pk[m][0], pk[m][1]};                                     \
        }                                                                        \
    } while (0)

    // GEMM2(chunk): wave q owns out-channels [q*64, +64); K = 64 FFI of chunk
#define GEMM2(c_, src_) do {                                                     \
        _Pragma("unroll")                                                        \
        for (int ks = 0; ks < 2; ++ks) {                                         \
            short8 a2[4], b2[4];                                                 \
            _Pragma("unroll")                                                    \
            for (int m = 0; m < 4; ++m) {                                        \
                int row = m * 16 + l15;                                          \
                int ph  = (ks * 4 + lg) ^ (row & 7);                             \
                a2[m] = *(const short8*)((const char*)(src_) + row * 128 + ph * 16); \
            }                                                                    \
            _Pragma("unroll")                                                    \
            for (int n = 0; n < 4; ++n)                                          \
                b2[n] = *(const short8*)(w2t + (size_t)((q * 4 + n) * 16 + (c_) * 2 + ks) * 512 + wlane); \
            _Pragma("unroll")                                                    \
            for (int n = 0; n < 4; ++n)                                          \
            _Pragma("unroll")                                                    \
            for (int m = 0; m < 4; ++m)                                          \
                acc2[n][m] = __builtin_amdgcn_mfma_f32_16x16x32_bf16(a2[m], b2[n], acc2[n][m], 0, 0, 0); \
        }                                                                        \
    } while (0)

    GEMM1C();          // chunk 0 (weights prefetched at kernel entry)
    PREFETCH_W1(1);    // issued BEFORE the barrier -> in flight across it
    VALWRITE(val[0]);
    BAR();
#pragma unroll
    for (int c = 0; c < 8; ++c) {
        if (c < 7) GEMM1C();            // chunk c+1: weights already in regs
        if (c < 6) PREFETCH_W1(c + 2);  // issue before this chunk's barrier
        GEMM2(c, val[c & 1]);
        if (c < 7) {
            VALWRITE(val[(c + 1) & 1]); // other buffer: readers done at last BAR
            BAR();
        }
    }

    // ---- epilogue: + attn row, f32x4 stores (4 consecutive positions) ----
    float* ob = out + (size_t)b * CDIM * HW;
#pragma unroll
    for (int n = 0; n < 4; ++n) {
        int c = q * 64 + n * 16 + l15;
#pragma unroll
        for (int m = 0; m < 4; ++m) {
            f32x4 r = acc2[n][m];
            r[0] += att[n]; r[1] += att[n]; r[2] += att[n]; r[3] += att[n];
            *(f32x4*)(ob + (size_t)c * HW + p0 + m * 16 + lg * 4) = r;
        }
    }
#undef PREFETCH_W1
#undef GEMM1C
#undef GEMM2
#undef VALWRITE
}

// ---------------------------------------------------------------------------
extern "C" void kernel_launch(void* const* d_in, const int* in_sizes, int n_in,
                              void* d_out, int out_size, void* d_ws, size_t ws_size,
                              hipStream_t stream) {
    const float* cnn   = (const float*)d_in[0];
    const float* extra = (const float*)d_in[1];
    const float* ln1_g = (const float*)d_in[2];
    const float* ln1_b = (const float*)d_in[3];
    const float* ln2_g = (const float*)d_in[4];
    const float* ln2_b = (const float*)d_in[5];
    // d_in[6] = Wq — provably unused
    const float* Wkv   = (const float*)d_in[7];
    const float* Wout  = (const float*)d_in[8];
    const float* W1    = (const float*)d_in[9];
    const float* W2    = (const float*)d_in[10];
    float* out = (float*)d_out;

    char* ws = (char*)d_ws;
    float* attn_part = (float*)ws;                         // 64 KiB (4x16x256)
    u16*   w1t       = (u16*)(ws + 64 * 1024);             // 512 KiB
    u16*   w2t       = (u16*)(ws + 64 * 1024 + 512 * 1024);// 256 KiB

    prep_kernel<<<160, 256, 0, stream>>>(extra, ln2_g, ln2_b, Wkv, Wout, W1, W2,
                                         attn_part, w1t, w2t);
    main_kernel<<<BATCH * 64, 256, 0, stream>>>(cnn, ln1_g, ln1_b, w1t, w2t,
                                                attn_part, out);
}